// Round 1
// baseline (1076.714 us; speedup 1.0000x reference)
//
#include <hip/hip_runtime.h>
#include <cstdint>

// Problem constants (fixed dataset: setup_inputs in reference)
constexpr int B = 8, N = 100000, G = 64, T = 256, TOPK = 27;
constexpr int CAP = 2048;           // candidate LDS capacity per gt
#define NEG_INF_VAL (-100000000.0f) // -INF in reference, exactly representable

// ---------------------------------------------------------------------------
// Kernel A: one block per (b,g). Finds exact top-27 nearest anchors by center
// distance (tie-break: lower index, matching lax.top_k), computes candidate
// IoUs, mean + unbiased std threshold, center-inside test, and scatters
// positives into a per-anchor best buffer via packed atomicMax.
// packed = (f32bits(iou) << 32) | (0xFFFFFFFF - g)
//   -> max = largest iou; tie -> smallest g (matches jnp.argmax first-max).
// packed == 0 means "unmatched" (positives always have iou > 0).
// ---------------------------------------------------------------------------
__global__ __launch_bounds__(256) void atss_assign_kernel(
    const float* __restrict__ anchors,   // [B,N,4]
    const float* __restrict__ gts,       // [B,G,4]
    unsigned long long* __restrict__ best) // [B*N]
{
#pragma clang fp contract(off)
  __shared__ float s_d[CAP];
  __shared__ int   s_i[CAP];
  __shared__ int   s_cnt;
  __shared__ unsigned long long s_wmin[4];
  __shared__ int   s_sel[TOPK];
  __shared__ float s_iou[TOPK];
  __shared__ int   s_in[TOPK];
  __shared__ float s_thresh;

  const int bg  = blockIdx.x;
  const int b   = bg / G;
  const int g   = bg % G;
  const int tid = threadIdx.x;

  const float4 gbox = ((const float4*)gts)[bg];
  const float g_cx = (gbox.z + gbox.x) * 0.5f;
  const float g_cy = (gbox.w + gbox.y) * 0.5f;

  const float4* abase = (const float4*)(anchors + (size_t)b * N * 4);

  // --- Candidate collection: all anchors with dist < thr (exact count). ---
  // If thr captures >= 27 anchors, the global top-27 are all in the set.
  float thr = 24.0f;
  int M = 0;
  for (int attempt = 0; attempt < 8; ++attempt) {
    if (tid == 0) s_cnt = 0;
    __syncthreads();
    for (int n = tid; n < N; n += 256) {
      float4 ab = abase[n];
      float acx = (ab.z + ab.x) * 0.5f;
      float acy = (ab.w + ab.y) * 0.5f;
      float dx = acx - g_cx, dy = acy - g_cy;
      float d = __fsqrt_rn(__fmul_rn(dx, dx) + __fmul_rn(dy, dy));
      if (d < thr) {
        int p = atomicAdd(&s_cnt, 1);
        if (p < CAP) { s_d[p] = d; s_i[p] = n; }
      }
    }
    __syncthreads();
    int cnt = s_cnt;
    __syncthreads();
    if (cnt >= TOPK && cnt <= CAP) { M = cnt; break; }
    thr = (cnt < TOPK) ? thr * 4.0f : thr * 0.5f;
  }

  // --- Exact top-27 selection: 27 rounds of block argmin over (d, idx). ---
  // pack = dbits(32) | anchor_idx(17) | slot(11)  -> lexicographic min.
  for (int k = 0; k < TOPK; ++k) {
    unsigned long long lm = ~0ULL;
    for (int s = tid; s < M; s += 256) {
      unsigned long long pk =
          ((unsigned long long)__float_as_uint(s_d[s]) << 28) |
          ((unsigned long long)(unsigned)s_i[s] << 11) |
          (unsigned long long)(unsigned)s;
      if (pk < lm) lm = pk;
    }
    for (int off = 32; off > 0; off >>= 1) {
      unsigned long long o = __shfl_xor(lm, off, 64);
      if (o < lm) lm = o;
    }
    if ((tid & 63) == 0) s_wmin[tid >> 6] = lm;
    __syncthreads();
    if (tid == 0) {
      unsigned long long m0 = s_wmin[0] < s_wmin[1] ? s_wmin[0] : s_wmin[1];
      unsigned long long m1 = s_wmin[2] < s_wmin[3] ? s_wmin[2] : s_wmin[3];
      unsigned long long m  = m0 < m1 ? m0 : m1;
      int slot = (int)(m & 0x7FFULL);
      s_sel[k] = (int)((m >> 11) & 0x1FFFFULL);
      s_d[slot] = __uint_as_float(0x7F800000u); // +inf: exclude next rounds
    }
    __syncthreads();
  }

  // --- Candidate IoU + center-inside test. ---
  if (tid < TOPK) {
    int a = s_sel[tid];
    float4 ab = abase[a];
    float area_a = __fmul_rn(ab.z - ab.x, ab.w - ab.y);
    float area_b = __fmul_rn(gbox.z - gbox.x, gbox.w - gbox.y);
    float ltx = fmaxf(ab.x, gbox.x), lty = fmaxf(ab.y, gbox.y);
    float rbx = fminf(ab.z, gbox.z), rby = fminf(ab.w, gbox.w);
    float w = fmaxf(rbx - ltx, 0.0f), h = fmaxf(rby - lty, 0.0f);
    float inter = __fmul_rn(w, h);
    float uni = (area_a + area_b) - inter;
    s_iou[tid] = inter / uni;
    float acx = (ab.z + ab.x) * 0.5f, acy = (ab.w + ab.y) * 0.5f;
    float l = acx - gbox.x, t = acy - gbox.y;
    float r = gbox.z - acx, bt = gbox.w - acy;
    float mn = fminf(fminf(l, t), fminf(r, bt));
    s_in[tid] = (mn > 0.01f) ? 1 : 0;
  }
  __syncthreads();

  // --- mean + unbiased std threshold (ddof=1). ---
  if (tid == 0) {
    float sum = 0.0f;
    for (int k = 0; k < TOPK; ++k) sum += s_iou[k];
    float mean = sum / (float)TOPK;
    float vs = 0.0f;
    for (int k = 0; k < TOPK; ++k) {
      float d = s_iou[k] - mean;
      vs += __fmul_rn(d, d);
    }
    float sd = __fsqrt_rn(vs / (float)(TOPK - 1));
    s_thresh = mean + sd;
  }
  __syncthreads();

  // --- Scatter positives. ---
  if (tid < TOPK) {
    float iou = s_iou[tid];
    if (s_in[tid] && iou >= s_thresh) {
      unsigned long long pk =
          ((unsigned long long)__float_as_uint(iou) << 32) |
          (unsigned long long)(0xFFFFFFFFu - (unsigned)g);
      atomicMax(&best[(size_t)b * N + s_sel[tid]], pk);
    }
  }
}

// ---------------------------------------------------------------------------
// Kernel B: one wave per anchor. Emits value, index(as float), matched_gts,
// and the 256-float token row (64 lanes x float4 = 1KB coalesced store).
// ---------------------------------------------------------------------------
__global__ __launch_bounds__(256) void atss_write_kernel(
    const unsigned long long* __restrict__ best, // [B*N]
    const float* __restrict__ gts,               // [B,G,4]
    const float* __restrict__ tokens,            // [B,G,T]
    float* __restrict__ out)
{
  constexpr int BN = B * N;
  float* __restrict__ out_val = out;
  float* __restrict__ out_idx = out + (size_t)BN;
  float* __restrict__ out_mg  = out + (size_t)2 * BN;
  float* __restrict__ out_tok = out + (size_t)6 * BN;

  const int lane = threadIdx.x & 63;
  const int wid  = (blockIdx.x * blockDim.x + threadIdx.x) >> 6;
  const int nw   = (gridDim.x * blockDim.x) >> 6;

  for (int i = wid; i < BN; i += nw) {
    unsigned long long p = best[i];
    int g = 0;
    float val = NEG_INF_VAL;
    if (p != 0ULL) {
      g   = (int)(0xFFFFFFFFu - (unsigned)(p & 0xFFFFFFFFULL));
      val = __uint_as_float((unsigned)(p >> 32));
    }
    const int b_  = i / N;
    const int row = b_ * G + g;

    float4 t;
    if (p != 0ULL) {
      t = ((const float4*)(tokens + (size_t)row * T))[lane];
    } else {
      t = make_float4(0.0f, 0.0f, 0.0f, 0.0f);
      if (lane == 63) t.w = 1.0f; // unmatched one-hot at token T-1
    }
    ((float4*)(out_tok + (size_t)i * T))[lane] = t;

    if (lane == 0) {
      out_val[i] = val;
    } else if (lane == 1) {
      out_idx[i] = (float)g;
    } else if (lane >= 2 && lane < 6) {
      out_mg[(size_t)i * 4 + (lane - 2)] = gts[(size_t)row * 4 + (lane - 2)];
    }
  }
}

extern "C" void kernel_launch(void* const* d_in, const int* in_sizes, int n_in,
                              void* d_out, int out_size, void* d_ws, size_t ws_size,
                              hipStream_t stream) {
  const float* anchors = (const float*)d_in[0]; // [B,N,4]
  const float* gts     = (const float*)d_in[1]; // [B,G,4]
  const float* tokens  = (const float*)d_in[2]; // [B,G,T]
  float* out = (float*)d_out;
  unsigned long long* best = (unsigned long long*)d_ws; // B*N u64 = 6.4 MB

  hipMemsetAsync(best, 0, sizeof(unsigned long long) * (size_t)B * N, stream);
  atss_assign_kernel<<<B * G, 256, 0, stream>>>(anchors, gts, best);
  atss_write_kernel<<<4096, 256, 0, stream>>>(best, gts, tokens, out);
}

// Round 2
// 960.042 us; speedup vs baseline: 1.1215x; 1.1215x over previous
//
#include <hip/hip_runtime.h>
#include <cstdint>

// Problem constants (fixed dataset: setup_inputs in reference)
constexpr int B = 8, N = 100000, G = 64, T = 256, TOPK = 27;
constexpr int BN = B * N;
constexpr int CAP = 2048;           // candidate LDS capacity per gt
#define NEG_INF_VAL (-100000000.0f) // -INF in reference, exactly representable

// ---------------------------------------------------------------------------
// Kernel 0: precompute anchor centers (float2) once. Same formula as the
// assign/iou phases so distances are bit-identical.
// ---------------------------------------------------------------------------
__global__ __launch_bounds__(256) void atss_centers_kernel(
    const float* __restrict__ anchors, float2* __restrict__ ctr)
{
#pragma clang fp contract(off)
  int i = blockIdx.x * 256 + threadIdx.x;
  if (i < BN) {
    float4 ab = ((const float4*)anchors)[i];
    ctr[i] = make_float2((ab.z + ab.x) * 0.5f, (ab.w + ab.y) * 0.5f);
  }
}

// ---------------------------------------------------------------------------
// Kernel A: one block per (b,g). Exact top-27 nearest anchors by center
// distance (tie-break: lower index, matching lax.top_k), candidate IoUs,
// mean + unbiased std threshold, center-inside test, packed atomicMax
// scatter into per-anchor best buffer.
// packed = (f32bits(iou) << 32) | (0xFFFFFFFF - g)
//   -> max = largest iou; tie -> smallest g (matches jnp.argmax first-max).
// packed == 0 means "unmatched" (positives always have iou > 0).
// ---------------------------------------------------------------------------
__global__ __launch_bounds__(256) void atss_assign_kernel(
    const float* __restrict__ anchors,     // [B,N,4]
    const float2* __restrict__ ctr,        // [B,N]
    const float* __restrict__ gts,         // [B,G,4]
    unsigned long long* __restrict__ best) // [B*N]
{
#pragma clang fp contract(off)
  __shared__ float s_d[CAP];
  __shared__ int   s_i[CAP];
  __shared__ int   s_cnt;
  __shared__ int   s_sel[TOPK];
  __shared__ float s_iou[TOPK];
  __shared__ int   s_in[TOPK];
  __shared__ float s_thresh;

  const int bg  = blockIdx.x;
  const int b   = bg / G;
  const int g   = bg % G;
  const int tid = threadIdx.x;

  const float4 gbox = ((const float4*)gts)[bg];
  const float g_cx = (gbox.z + gbox.x) * 0.5f;
  const float g_cy = (gbox.w + gbox.y) * 0.5f;

  const float4*  abase = (const float4*)(anchors + (size_t)b * N * 4);
  const float2*  cbase = ctr + (size_t)b * N;

  // --- Candidate collection: all anchors with dist < thr (exact count). ---
  // If thr captures >= 27 anchors, the true top-27 are all in the set.
  float thr = 24.0f;
  int M = 0;
  for (int attempt = 0; attempt < 8; ++attempt) {
    if (tid == 0) s_cnt = 0;
    __syncthreads();
    for (int n = tid; n < N; n += 256) {
      float2 c = cbase[n];
      float dx = c.x - g_cx, dy = c.y - g_cy;
      float d = __fsqrt_rn(__fmul_rn(dx, dx) + __fmul_rn(dy, dy));
      if (d < thr) {
        int p = atomicAdd(&s_cnt, 1);
        if (p < CAP) { s_d[p] = d; s_i[p] = n; }
      }
    }
    __syncthreads();
    int cnt = s_cnt;
    __syncthreads();
    if (cnt >= TOPK && cnt <= CAP) { M = cnt; break; }
    thr = (cnt < TOPK) ? thr * 4.0f : thr * 0.5f;
  }

  // --- Exact top-27 by rank counting over (d, idx) lexicographic keys. ---
  // Keys are distinct (idx unique) -> ranks unique; rank k = k-th nearest,
  // same order the 27-round argmin produced (preserves mean/std sum order).
  for (int s = tid; s < M; s += 256) {
    unsigned long long pk_s =
        ((unsigned long long)__float_as_uint(s_d[s]) << 20) |
        (unsigned long long)(unsigned)s_i[s];
    int rank = 0;
    for (int j = 0; j < M; ++j) {
      unsigned long long pk_j =
          ((unsigned long long)__float_as_uint(s_d[j]) << 20) |
          (unsigned long long)(unsigned)s_i[j];
      rank += (pk_j < pk_s) ? 1 : 0;
    }
    if (rank < TOPK) s_sel[rank] = s_i[s];
  }
  __syncthreads();

  // --- Candidate IoU + center-inside test. ---
  if (tid < TOPK) {
    int a = s_sel[tid];
    float4 ab = abase[a];
    float area_a = __fmul_rn(ab.z - ab.x, ab.w - ab.y);
    float area_b = __fmul_rn(gbox.z - gbox.x, gbox.w - gbox.y);
    float ltx = fmaxf(ab.x, gbox.x), lty = fmaxf(ab.y, gbox.y);
    float rbx = fminf(ab.z, gbox.z), rby = fminf(ab.w, gbox.w);
    float w = fmaxf(rbx - ltx, 0.0f), h = fmaxf(rby - lty, 0.0f);
    float inter = __fmul_rn(w, h);
    float uni = (area_a + area_b) - inter;
    s_iou[tid] = inter / uni;
    float acx = (ab.z + ab.x) * 0.5f, acy = (ab.w + ab.y) * 0.5f;
    float l = acx - gbox.x, t = acy - gbox.y;
    float r = gbox.z - acx, bt = gbox.w - acy;
    float mn = fminf(fminf(l, t), fminf(r, bt));
    s_in[tid] = (mn > 0.01f) ? 1 : 0;
  }
  __syncthreads();

  // --- mean + unbiased std threshold (ddof=1). Same order as round 1. ---
  if (tid == 0) {
    float sum = 0.0f;
    for (int k = 0; k < TOPK; ++k) sum += s_iou[k];
    float mean = sum / (float)TOPK;
    float vs = 0.0f;
    for (int k = 0; k < TOPK; ++k) {
      float d = s_iou[k] - mean;
      vs += __fmul_rn(d, d);
    }
    float sd = __fsqrt_rn(vs / (float)(TOPK - 1));
    s_thresh = mean + sd;
  }
  __syncthreads();

  // --- Scatter positives. ---
  if (tid < TOPK) {
    float iou = s_iou[tid];
    if (s_in[tid] && iou >= s_thresh) {
      unsigned long long pk =
          ((unsigned long long)__float_as_uint(iou) << 32) |
          (unsigned long long)(0xFFFFFFFFu - (unsigned)g);
      atomicMax(&best[(size_t)b * N + s_sel[tid]], pk);
    }
  }
}

// ---------------------------------------------------------------------------
// Kernel B: one block per 256 anchors.
// Phase 1: coalesced best[] load; emit val/idx (dword) and matched_gts
//          (float4) coalesced; stash matched token row index in LDS.
// Phase 2: 64 steps x 4 anchors: block cooperatively streams token rows,
//          4 KB contiguous store per step; loads independent -> pipelined.
// ---------------------------------------------------------------------------
__global__ __launch_bounds__(256) void atss_write_kernel(
    const unsigned long long* __restrict__ best, // [B*N]
    const float* __restrict__ gts,               // [B,G,4]
    const float* __restrict__ tokens,            // [B,G,T]
    float* __restrict__ out)
{
  float* __restrict__ out_val = out;
  float* __restrict__ out_idx = out + (size_t)BN;
  float* __restrict__ out_mg  = out + (size_t)2 * BN;
  float* __restrict__ out_tok = out + (size_t)6 * BN;

  __shared__ int s_row[256]; // gt row (b*G+g) if matched, else -1

  const int tid = threadIdx.x;
  const int i0  = blockIdx.x * 256;
  const int i   = i0 + tid;

  // --- Phase 1 ---
  unsigned long long p = best[i];
  const int b_ = i / N;
  int g = 0;
  float val = NEG_INF_VAL;
  if (p != 0ULL) {
    g   = (int)(0xFFFFFFFFu - (unsigned)(p & 0xFFFFFFFFULL));
    val = __uint_as_float((unsigned)(p >> 32));
  }
  const int row = b_ * G + g; // unmatched -> g=0 (matches argmax of all -INF)
  s_row[tid] = (p != 0ULL) ? row : -1;

  out_val[i] = val;
  out_idx[i] = (float)g;
  ((float4*)out_mg)[i] = ((const float4*)gts)[row];
  __syncthreads();

  // --- Phase 2: token rows ---
  const int lane = tid & 63;
  const int sub  = tid >> 6; // 0..3: which anchor within the step
  const float4* tok4 = (const float4*)tokens;
#pragma unroll 4
  for (int s = 0; s < 64; ++s) {
    int a = (s << 2) + sub;
    int r = s_row[a];
    float4 t;
    if (r >= 0) {
      t = tok4[(size_t)r * 64 + lane];
    } else {
      t = make_float4(0.0f, 0.0f, 0.0f, 0.0f);
      if (lane == 63) t.w = 1.0f; // unmatched one-hot at token T-1
    }
    ((float4*)(out_tok + (size_t)(i0 + a) * T))[lane] = t;
  }
}

extern "C" void kernel_launch(void* const* d_in, const int* in_sizes, int n_in,
                              void* d_out, int out_size, void* d_ws, size_t ws_size,
                              hipStream_t stream) {
  const float* anchors = (const float*)d_in[0]; // [B,N,4]
  const float* gts     = (const float*)d_in[1]; // [B,G,4]
  const float* tokens  = (const float*)d_in[2]; // [B,G,T]
  float* out = (float*)d_out;

  unsigned long long* best = (unsigned long long*)d_ws;        // B*N u64 = 6.4 MB
  float2* ctr = (float2*)((char*)d_ws + sizeof(unsigned long long) * (size_t)BN);

  hipMemsetAsync(best, 0, sizeof(unsigned long long) * (size_t)BN, stream);
  atss_centers_kernel<<<(BN + 255) / 256, 256, 0, stream>>>(anchors, ctr);
  atss_assign_kernel<<<B * G, 256, 0, stream>>>(anchors, ctr, gts, best);
  atss_write_kernel<<<BN / 256, 256, 0, stream>>>(best, gts, tokens, out);
}